// Round 13
// baseline (170.708 us; speedup 1.0000x reference)
//
#include <hip/hip_runtime.h>
#include <stdint.h>

#define D_MODEL 1024
#define NHEADS  16
#define DHEAD   64
#define BATCH   4
#define SEQ     2048
#define MTOT    (BATCH*SEQ)

typedef unsigned short u16;
typedef uint32_t u32;
typedef __bf16 bf16x8 __attribute__((ext_vector_type(8)));
typedef float  f32x4  __attribute__((ext_vector_type(4)));
typedef float  f32x16 __attribute__((ext_vector_type(16)));
typedef u16    u16x8  __attribute__((ext_vector_type(8)));
typedef u16    u16x4  __attribute__((ext_vector_type(4)));
typedef u32    u32x2  __attribute__((ext_vector_type(2)));
typedef u32    u32x4  __attribute__((ext_vector_type(4)));

__device__ __forceinline__ u16 f2bf(float f) {
  uint32_t u = __builtin_bit_cast(uint32_t, f);
  u += 0x7fff + ((u >> 16) & 1);   // RNE
  return (u16)(u >> 16);
}

__device__ __forceinline__ void gll16(const u16* g, u16* lds) {
  __builtin_amdgcn_global_load_lds(
      (__attribute__((address_space(1))) void*)(g),
      (__attribute__((address_space(3))) void*)(lds), 16, 0, 0);
}

// 4 weight matrices in one launch
__global__ void cvtk4(const float4* __restrict__ a, const float4* __restrict__ b,
                      const float4* __restrict__ c, const float4* __restrict__ d,
                      u16x4* __restrict__ out, int n4) {
  const int i = blockIdx.x * blockDim.x + threadIdx.x;
  if (i >= n4) return;
  const float4* src = (blockIdx.y == 0) ? a : (blockIdx.y == 1) ? b
                    : (blockIdx.y == 2) ? c : d;
  const float4 f = src[i];
  u16x4 h;
  h[0] = f2bf(f.x); h[1] = f2bf(f.y); h[2] = f2bf(f.z); h[3] = f2bf(f.w);
  out[(size_t)blockIdx.y * n4 + i] = h;
}

#define QS 8192   // u16 per 16KB slot
#define BARS() __builtin_amdgcn_s_barrier()
#define LGKM0() do { asm volatile("s_waitcnt lgkmcnt(0)" ::: "memory"); \
                     __builtin_amdgcn_sched_barrier(0); } while (0)

// ---------------------------------------------------------------------------
// Fused cvt+QKV GEMM, BN=192 2-round packing (512 blocks), fp32 A input.
// C[8192x3072] = X_fp32[8192x1024] * W^T(bf16). BM=256, BN=192, BK=64.
// A-staging is reg-staged with in-flight fp32->bf16 conversion (T14 split):
//  p1: issue 8x global_load_dwordx4 of X(t+2) (lane-consecutive, 256B segs)
//  p2: cvt_pk x16 -> 8x ds_write_b64 into swizzled slot-A (c' = c^(r&7)).
// araw dependency is compiler-tracked (auto waitcnt); B stays gll16 with
// manual end-of-tile vmcnt(0) (only B(t+1)[3] outstanding there).
// Slot reuse: A(t+2) written at t.p2; slot's A last read at t.p1 (barrier
// pair between). B(t+1) staged t.p1, completed by tile-end vmcnt(0)+BAR.
// Epilogue: per-column z/scale, permuted bf16 store.
// ---------------------------------------------------------------------------
#define QP3 28672   // u16 per parity (56KB): A0 @0, A1 @8192, B @16384

#define QF_AISSUE(t_) do {                                                        \
    _Pragma("unroll")                                                             \
    for (int j = 0; j < 8; ++j) {                                                 \
      const int rr_ = j*32 + w*4 + (l >> 4);                                      \
      araw[j] = *(const float4*)(A32 + (size_t)(m0 + rr_)*1024 + (t_)*64 + (l & 15)*4); \
    }                                                                             \
  } while (0)

#define QF_AWRITE(poff) do {                                                      \
    _Pragma("unroll")                                                             \
    for (int j = 0; j < 8; ++j) {                                                 \
      const int rr_ = j*32 + w*4 + (l >> 4);                                      \
      u32 c0_, c1_;                                                               \
      asm("v_cvt_pk_bf16_f32 %0, %1, %2" : "=v"(c0_) : "v"(araw[j].x), "v"(araw[j].y)); \
      asm("v_cvt_pk_bf16_f32 %0, %1, %2" : "=v"(c1_) : "v"(araw[j].z), "v"(araw[j].w)); \
      const int pic_ = l & 15;                                                    \
      const int c_ = pic_ >> 1, hf_ = pic_ & 1;                                   \
      const int off_ = ((rr_ & 128) ? 8192 : 0) + (rr_ & 127)*64                  \
                       + ((c_ ^ (rr_ & 7)) << 3) + hf_*4;                         \
      *(u32x2*)&qsm[(poff) + off_] = u32x2{c0_, c1_};                             \
    }                                                                             \
  } while (0)

#define Q3_BSTG(t_, dstoff) do {                                                  \
    gll16(pB + (size_t)0*1024  + (t_)*64, qsm + (dstoff) + w*1536);               \
    gll16(pB + (size_t)8*1024  + (t_)*64, qsm + (dstoff) + w*1536 + 512);         \
    gll16(pB + (size_t)16*1024 + (t_)*64, qsm + (dstoff) + w*1536 + 1024);        \
  } while (0)

#define Q3_READS_P1() do {                                                        \
    _Pragma("unroll")                                                             \
    for (int mf = 0; mf < 8; ++mf) {                                              \
      af0[mf] = *(const bf16x8*)&sA[(mf*16 + r15)*64 + cs0];                      \
      af1[mf] = *(const bf16x8*)&sA[(mf*16 + r15)*64 + cs1];                      \
    }                                                                             \
    _Pragma("unroll")                                                             \
    for (int nf = 0; nf < 3; ++nf)                                                \
      bq[nf] = *(const bf16x8*)&sB[(brow + nf*16 + r15)*64 + cs0];                \
  } while (0)

#define Q3_READS_P2() do {                                                        \
    _Pragma("unroll")                                                             \
    for (int nf = 0; nf < 3; ++nf)                                                \
      bq[nf] = *(const bf16x8*)&sB[(brow + nf*16 + r15)*64 + cs1];                \
  } while (0)

#define Q3_MM(AF) do {                                                            \
    __builtin_amdgcn_s_setprio(1);                                                \
    _Pragma("unroll")                                                             \
    for (int mf = 0; mf < 8; ++mf)                                                \
      _Pragma("unroll")                                                           \
      for (int nf = 0; nf < 3; ++nf)                                              \
        acc[mf][nf] = __builtin_amdgcn_mfma_f32_16x16x32_bf16(AF[mf], bq[nf],     \
                                                              acc[mf][nf], 0,0,0);\
    __builtin_amdgcn_s_setprio(0);                                                \
  } while (0)

__global__ __launch_bounds__(512, 2) void gemm_qkvf(
    const float* __restrict__ A32, const u16* __restrict__ Bw, u16* __restrict__ Out)
{
  extern __shared__ u16 qsm[];   // 112 KB
  const int tid = threadIdx.x;
  const int w = tid >> 6, l = tid & 63;
  const int wm = w >> 2, wn = w & 3;
  const int bid = blockIdx.x;
  const int wg = (bid & 7) * 64 + (bid >> 3);   // XCD-pinned (512 = 8*64)
  const int m0 = (wg >> 4) * 256, n0 = (wg & 15) * 192;

  // B staging: lane row (l>>3), pre-swizzled source chunk
  const int sc8 = ((l & 7) ^ ((l >> 3) & 7)) * 8;
  const u16* pB = Bw + (size_t)(n0 + 24*w + (l >> 3)) * 1024 + sc8;

  const int r15 = l & 15;
  const int cs0 = (((l >> 4) + 0) ^ (l & 7)) * 8;
  const int cs1 = (((l >> 4) + 4) ^ (l & 7)) * 8;
  const int brow = wn * 48;

  f32x4 acc[8][3];
  #pragma unroll
  for (int i = 0; i < 8; ++i)
    #pragma unroll
    for (int j = 0; j < 3; ++j)
      acc[i][j] = f32x4{0.f, 0.f, 0.f, 0.f};

  float4 araw[8];

  // prologue: A(0), A(1) via reg-stage; B(0) gll16; full drain
  QF_AISSUE(0);
  QF_AWRITE(0);
  QF_AISSUE(1);
  QF_AWRITE(QP3);
  Q3_BSTG(0, 16384);
  asm volatile("s_waitcnt vmcnt(0)" ::: "memory");
  BARS();
  LGKM0();

  #pragma unroll 2
  for (int t = 0; t < 14; ++t) {
    const int p = t & 1, po = p ^ 1;
    const u16* sA = qsm + (size_t)p*QP3 + (size_t)wm*8192;
    const u16* sB = qsm + (size_t)p*QP3 + 16384;
    bf16x8 af0[8], af1[8], bq[3];
    // p1: all A/B.ks0 reads; issue A(t+2) fp32 loads; stage B(t+1)
    Q3_READS_P1();
    QF_AISSUE(t+2);
    Q3_BSTG(t+1, po*QP3 + 16384);
    BARS(); LGKM0();
    Q3_MM(af0);
    BARS();
    // p2: B.ks1 reads; cvt+write A(t+2) -> slot p (A read finished at p1)
    Q3_READS_P2();
    QF_AWRITE(p*QP3);
    BARS(); LGKM0();
    Q3_MM(af1);
    asm volatile("s_waitcnt vmcnt(0)" ::: "memory");  // B(t+1) complete
    BARS();
    __builtin_amdgcn_sched_barrier(0);
  }

  { // peeled t = 14 (p=0): p1 stages B(15) only; no A(16)
    const u16* sA = qsm + (size_t)wm*8192;
    const u16* sB = qsm + 16384;
    bf16x8 af0[8], af1[8], bq[3];
    Q3_READS_P1();
    Q3_BSTG(15, QP3 + 16384);
    BARS(); LGKM0();
    Q3_MM(af0);
    BARS();
    Q3_READS_P2();
    BARS(); LGKM0();
    Q3_MM(af1);
    asm volatile("s_waitcnt vmcnt(0)" ::: "memory");  // B(15) complete
    BARS();
    __builtin_amdgcn_sched_barrier(0);
  }
  { // peeled t = 15 (p=1): plain compute
    const u16* sA = qsm + (size_t)QP3 + (size_t)wm*8192;
    const u16* sB = qsm + (size_t)QP3 + 16384;
    bf16x8 af0[8], af1[8], bq[3];
    Q3_READS_P1();
    Q3_MM(af0);
    Q3_READS_P2();
    Q3_MM(af1);
  }

  // epilogue: per-column z/scale, permuted bf16 store
  const float qs = 0.125f * 1.44269504088896f;
  const int g = l >> 4, c15 = l & 15;
  #pragma unroll
  for (int mf = 0; mf < 8; ++mf) {
    #pragma unroll
    for (int nf = 0; nf < 3; ++nf) {
      #pragma unroll
      for (int j = 0; j < 4; ++j) {
        const int row = m0 + wm*128 + mf*16 + g*4 + j;
        const int col = n0 + wn*48 + nf*16 + c15;
        const int z = col >> 10;
        const int wi = col & 1023;
        const float scale = (z == 0) ? qs : 1.0f;
        const int b = row >> 11, sq = row & (SEQ-1);
        const int h = wi >> 6, dh = wi & (DHEAD-1);
        Out[(size_t)z * MTOT * D_MODEL
            + ((size_t)(b*NHEADS + h) * SEQ + sq) * DHEAD + dh] =
            f2bf(acc[mf][nf][j] * scale);
      }
    }
  }
}

#undef QF_AISSUE
#undef QF_AWRITE
#undef Q3_BSTG
#undef Q3_READS_P1
#undef Q3_READS_P2
#undef Q3_MM

// ---------------------------------------------------------------------------
// Output projection GEMM (unchanged from R9): counted-vmcnt, 256 blocks.
// ---------------------------------------------------------------------------
#define OSTG(pbase, roff, t_, slot_) do {                                       \
    gll16((pbase) + (size_t)(roff)*1024 + (t_)*64,      osm + (slot_)*QS + w*512);        \
    gll16((pbase) + (size_t)((roff)+64)*1024 + (t_)*64, osm + (slot_)*QS + w*512 + 4096); \
  } while (0)

#define OREADS_P1() do {                                                        \
    _Pragma("unroll")                                                           \
    for (int mf = 0; mf < 8; ++mf) {                                            \
      af0[mf] = *(const bf16x8*)&sA[(mf*16 + r15)*64 + cs0];                    \
      af1[mf] = *(const bf16x8*)&sA[(mf*16 + r15)*64 + cs1];                    \
    }                                                                           \
    _Pragma("unroll")                                                           \
    for (int nf = 0; nf < 2; ++nf)                                              \
      bq[nf] = *(const bf16x8*)&sB[(brow + nf*16 + r15)*64 + cs0];              \
  } while (0)

#define OREADS_P2() do {                                                        \
    _Pragma("unroll")                                                           \
    for (int nf = 0; nf < 2; ++nf)                                              \
      bq[nf] = *(const bf16x8*)&sB[(brow + nf*16 + r15)*64 + cs1];              \
  } while (0)

#define OMM(AF) do {                                                            \
    __builtin_amdgcn_s_setprio(1);                                              \
    _Pragma("unroll")                                                           \
    for (int mf = 0; mf < 8; ++mf) {                                            \
      acc[mf][0] = __builtin_amdgcn_mfma_f32_16x16x32_bf16(AF[mf], bq[0],       \
                                                           acc[mf][0], 0,0,0);  \
      acc[mf][1] = __builtin_amdgcn_mfma_f32_16x16x32_bf16(AF[mf], bq[1],       \
                                                           acc[mf][1], 0,0,0);  \
    }                                                                           \
    __builtin_amdgcn_s_setprio(0);                                              \
  } while (0)

__global__ __launch_bounds__(512, 2) void gemm_o8p(
    const u16* __restrict__ A, const u16* __restrict__ Bw, float* __restrict__ Out)
{
  extern __shared__ u16 osm[];   // 6 * 16KB = 96KB
  const int tid = threadIdx.x;
  const int w = tid >> 6, l = tid & 63;
  const int wm = w >> 2, wn = w & 3;
  const int bid = blockIdx.x;
  const int wg = (bid & 7) * 32 + (bid >> 3);   // XCD-pinned (256 = 8*32)
  const int m0 = (wg >> 3) * 256, n0 = (wg & 7) * 128;

  const int sr  = 8*w + (l >> 3);
  const int sc8 = ((l & 7) ^ ((l >> 3) & 7)) * 8;
  const u16* pA = A  + (size_t)(m0 + sr) * 1024 + sc8;
  const u16* pB = Bw + (size_t)(n0 + sr) * 1024 + sc8;

  const int r15 = l & 15;
  const int cs0 = (((l >> 4) + 0) ^ (l & 7)) * 8;
  const int cs1 = (((l >> 4) + 4) ^ (l & 7)) * 8;
  const int brow = wn * 32;

  f32x4 acc[8][2];
  #pragma unroll
  for (int i = 0; i < 8; ++i) {
    acc[i][0] = f32x4{0.f, 0.f, 0.f, 0.f};
    acc[i][1] = f32x4{0.f, 0.f, 0.f, 0.f};
  }

  OSTG(pA, 0,   0, 0);
  OSTG(pA, 128, 0, 1);
  OSTG(pB, 0,   0, 2);
  OSTG(pA, 0,   1, 3);
  OSTG(pA, 128, 1, 4);
  asm volatile("s_waitcnt vmcnt(4)" ::: "memory");
  BARS();
  __builtin_amdgcn_sched_barrier(0);

  #pragma unroll 2
  for (int t = 0; t < 14; ++t) {
    const int p = t & 1, po = p ^ 1;
    const u16* sA = osm + (size_t)(p*3 + wm) * QS;
    const u16* sB = osm + (size_t)(p*3 + 2) * QS;
    bf16x8 af0[8], af1[8], bq[2];
    OREADS_P1();
    OSTG(pB, 0, t+1, po*3 + 2);
    BARS(); LGKM0();
    OMM(af0);
    BARS();
    OREADS_P2();
    OSTG(pA, 0,   t+2, p*3 + 0);
    OSTG(pA, 128, t+2, p*3 + 1);
    BARS(); LGKM0();
    OMM(af1);
    asm volatile("s_waitcnt vmcnt(4)" ::: "memory");
    BARS();
    __builtin_amdgcn_sched_barrier(0);
  }

  {
    const u16* sA = osm + (size_t)(0*3 + wm) * QS;
    const u16* sB = osm + (size_t)(0*3 + 2) * QS;
    bf16x8 af0[8], af1[8], bq[2];
    OREADS_P1();
    OSTG(pB, 0, 15, 1*3 + 2);
    BARS(); LGKM0();
    OMM(af0);
    BARS();
    OREADS_P2();
    BARS(); LGKM0();
    OMM(af1);
    asm volatile("s_waitcnt vmcnt(0)" ::: "memory");
    BARS();
    __builtin_amdgcn_sched_barrier(0);
  }
  {
    const u16* sA = osm + (size_t)(1*3 + wm) * QS;
    const u16* sB = osm + (size_t)(1*3 + 2) * QS;
    bf16x8 af0[8], af1[8], bq[2];
    OREADS_P1();
    OMM(af0);
    OREADS_P2();
    OMM(af1);
  }

  const int g = l >> 4, c15 = l & 15;
  #pragma unroll
  for (int mf = 0; mf < 8; ++mf) {
    #pragma unroll
    for (int nf = 0; nf < 2; ++nf) {
      #pragma unroll
      for (int j = 0; j < 4; ++j) {
        const int row = m0 + wm*128 + mf*16 + g*4 + j;
        const int col = n0 + wn*32 + nf*16 + c15;
        Out[(size_t)row * D_MODEL + col] = acc[mf][nf][j];
      }
    }
  }
}

#undef OSTG
#undef OREADS_P1
#undef OREADS_P2
#undef OMM

// ---------------------------------------------------------------------------
// Causal flash attention (attn6, best-measured 69.3us — unchanged):
// 8 warps x 32 q-rows, KVBLK=128, paired superblocks {p, 7-p}, grid 256,
// 32x32x16 MFMA, O^T form, T13 defer-max, swizzled K/V LDS.
// ---------------------------------------------------------------------------
__launch_bounds__(512, 2)
__global__ void attn6_k(const u16* __restrict__ Qb, const u16* __restrict__ Kb_,
                        const u16* __restrict__ Vb_, u16* __restrict__ Oa)
{
  const int tid = threadIdx.x;
  const int w = tid >> 6, l = tid & 63;
  const int q5 = l & 31, hi = l >> 5;
  const int r = blockIdx.x;
  const int bh = (r & 7) * 8 + ((r >> 3) & 7);
  const int pairi = r >> 6;                     // 0..3
  const int b = bh >> 4, h = bh & 15;
  const size_t base = (size_t)bh * SEQ * DHEAD;
  const u16* Qg = Qb + base;
  const u16* Kg = Kb_ + base;
  const u16* Vg = Vb_ + base;

  __shared__ __align__(16) u16 smem[32768];

  const int kc = tid & 7, rp = tid >> 3;
  const int vsub = rp >> 5;
  const int rp5 = rp & 31;
  int vIdx32[8];
  #pragma unroll
  for (int e = 0; e < 8; ++e)
    vIdx32[e] = vsub*2048 + (8*kc + e)*32 + ((((rp5 >> 2) ^ kc ^ e) & 7) << 2) + (rp5 & 3);

  const int kr8 = l >> 3;
  const int kkv = 8*w + kr8;
  const int kdc = (l & 7) ^ kr8 ^ w;

  for (int half = 0; half < 2; ++half) {
    const int tq = half ? (7 - pairi) : pairi;
    const int q0w = tq*256 + 32*w;
    const int ntk = (tq + 1) * 2;
    const int ntw = (q0w >> 7) + 1;

    bf16x8 qf[4];
    #pragma unroll
    for (int s = 0; s < 4; ++s)
      qf[s] = *(const bf16x8*)(Qg + (size_t)(q0w + q5)*DHEAD + 16*s + 8*hi);

    f32x16 c0 = {}, c1 = {};
    float mrun = -1e30f, lrun = 0.f;

    {
      #pragma unroll
      for (int h2 = 0; h2 < 2; ++h2)
        gll16(Kg + (size_t)(64*h2 + kkv)*DHEAD + kdc*8, smem + h2*4096 + w*512);
      const u16x8 v0 = *(const u16x8*)(Vg + (size_t)(2*rp)*DHEAD + kc*8);
      const u16x8 v1 = *(const u16x8*)(Vg + (size_t)(2*rp + 1)*DHEAD + kc*8);
      u32* Vd = (u32*)(smem + 16384);
      #pragma unroll
      for (int e = 0; e < 8; ++e)
        Vd[vIdx32[e]] = (u32)v0[e] | ((u32)v1[e] << 16);
    }
    __syncthreads();

    for (int t = 0; t < ntk; ++t) {
      const int cur = t & 1;
      const bool pf = (t + 1 < ntk);
      u16x8 v0, v1;
      if (pf) {
        const int kv1 = (t + 1) * 128;
        v0 = *(const u16x8*)(Vg + (size_t)(kv1 + 2*rp)*DHEAD + kc*8);
        v1 = *(const u16x8*)(Vg + (size_t)(kv1 + 2*rp + 1)*DHEAD + kc*8);
        #pragma unroll
        for (int h2 = 0; h2 < 2; ++h2)
          gll16(Kg + (size_t)(kv1 + 64*h2 + kkv)*DHEAD + kdc*8,
                smem + (cur^1)*8192 + h2*4096 + w*512);
      }

      if (t < ntw) {
        const u16* Kb = smem + cur*8192;
        const u16* Vv = smem + 16384 + cur*8192;

        f32x16 st[4] = {{}, {}, {}, {}};
        __builtin_amdgcn_s_setprio(1);
        #pragma unroll
        for (int kbg = 0; kbg < 4; ++kbg) {
          #pragma unroll
          for (int s = 0; s < 4; ++s) {
            const int slot = ((2*s + hi) ^ (l & 7) ^ ((4*(kbg & 1)) & 7) ^ (q5 >> 3)) & 7;
            const bf16x8 kf = *(const bf16x8*)(Kb + (kbg >> 1)*4096
                                               + ((kbg & 1)*32 + q5)*64 + slot*8);
            st[kbg] = __builtin_amdgcn_mfma_f32_32x32x16_bf16(kf, qf[s], st[kbg], 0, 0, 0);
          }
        }
        __builtin_amdgcn_s_setprio(0);

        if (t == ntw - 1) {
          const int kv0 = t * 128;
          #pragma unroll
          for (int kbg = 0; kbg < 4; ++kbg)
            #pragma unroll
            for (int rr = 0; rr < 16; ++rr) {
              const int kvg = kv0 + 32*kbg + (rr & 3) + 8*(rr >> 2) + 4*hi;
              if (kvg > q0w + q5) st[kbg][rr] = -1e30f;
            }
        }

        float mx = -1e30f;
        #pragma unroll
        for (int kbg = 0; kbg < 4; ++kbg)
          #pragma unroll
          for (int rr = 0; rr < 16; ++rr) mx = fmaxf(mx, st[kbg][rr]);
        mx = fmaxf(mx, __shfl_xor(mx, 32));
        float alpha = 1.0f;
        if (!__all(mx <= mrun + 8.0f)) {
          const float mnew = fmaxf(mrun, mx);
          alpha = __builtin_amdgcn_exp2f(mrun - mnew);
          mrun = mnew;
          #pragma unroll
          for (int rr = 0; rr < 16; ++rr) { c0[rr] *= alpha; c1[rr] *= alpha; }
        }
        float rs = 0.f;
        #pragma unroll
        for (int kbg = 0; kbg < 4; ++kbg)
          #pragma unroll
          for (int rr = 0; rr < 16; ++rr) {
            const float pe = __builtin_amdgcn_exp2f(st[kbg][rr] - mrun);
            st[kbg][rr] = pe;
            rs += pe;
          }
        rs += __shfl_xor(rs, 32);
        lrun = lrun * alpha + rs;

        bf16x8 pb[8];
        #pragma unroll
        for (int kbg = 0; kbg < 4; ++kbg) {
          u32 pw[8];
          #pragma unroll
          for (int i = 0; i < 8; ++i) {
            u32 t0;
            asm("v_cvt_pk_bf16_f32 %0, %1, %2"
                : "=v"(t0) : "v"(st[kbg][2*i]), "v"(st[kbg][2*i+1]));
            pw[i] = t0;
          }
          asm("v_permlane32_swap_b32 %0, %1" : "+v"(pw[0]), "+v"(pw[2]));
          asm("v_permlane32_swap_b32 %0, %1" : "+v"(pw[1]), "+v"(pw[3]));
          asm("v_permlane32_swap_b32 %0, %1" : "+v"(pw[4]), "+v"(pw[6]));
          asm("v_permlane32_swap_b32 %0, %1" : "+v"(pw[5]), "+v"(pw[7]));
          pb[2*kbg]   = __builtin_bit_cast(bf16x8, u32x4{pw[0], pw[1], pw[2], pw[3]});
          pb[2*kbg+1] = __builtin_bit_cast(bf16x8, u32x4{pw[4], pw[5], pw[6], pw[7]});
        }

        __builtin_amdgcn_s_setprio(1);
        #pragma unroll
        for (int h2 = 0; h2 < 2; ++h2) {
          #pragma unroll
          for (int s = 0; s < 4; ++s) {
            {
              const int slot = ((2*s + hi) ^ (l & 7) ^ (q5 >> 3)) & 7;
              const bf16x8 vf = *(const bf16x8*)(Vv + h2*4096 + q5*64 + slot*8);
              c0 = __builtin_amdgcn_mfma_f32_32x32x16_bf16(vf, pb[4*h2 + s], c0, 0, 0, 0);
            }
            {
              const int slot = ((2*s + hi) ^ (l & 7) ^ 4 ^ (q5 >> 3)) & 7;
              const bf16x8 vf = *(const bf16x8*)(Vv + h2*4096 + (32 + q5)*64 + slot*8);
              c1 = __builtin_amdgcn_mfma_f32_32x32x16_bf16(vf, pb[4*h2 + s], c1, 0, 0, 0);
            }
          }
        }
        __builtin_amdgcn_s_setprio(0);
      }

      if (pf) {
        u32* Vd = (u32*)(smem + 16384) + (cur^1)*4096;
        #pragma unroll
        for (int e = 0; e < 8; ++e)
          Vd[vIdx32[e]] = (u32)v0[e] | ((u32)v1[e] << 16);
      }
      __syncthreads();
    }

    const float linv = __builtin_amdgcn_rcpf(lrun);
    #pragma unroll
    for (int Ab = 0; Ab < 2; ++Ab)
      #pragma unroll
      for (int rr = 0; rr < 16; ++rr) {
        const int d = 32*Ab + (rr & 3) + 8*(rr >> 2) + 4*hi;
        smem[w*2048 + q5*64 + (((d >> 3) ^ (q5 & 7)) & 7)*8 + (d & 7)] =
            f2bf((Ab ? c1[rr] : c0[rr]) * linv);
      }
    __syncthreads();
    #pragma unroll
    for (int cc = 0; cc < 4; ++cc) {
      const int dchunk = 4*hi + cc;
      const u16x8 vv = *(const u16x8*)&smem[w*2048 + q5*64 + ((dchunk ^ (q5 & 7)) & 7)*8];
      *(u16x8*)(Oa + (size_t)(b*SEQ + q0w + q5)*D_MODEL + h*DHEAD + 32*hi + 8*cc) = vv;
    }
    __syncthreads();
  }
}

extern "C" void kernel_launch(void* const* d_in, const int* in_sizes, int n_in,
                              void* d_out, int out_size, void* d_ws, size_t ws_size,
                              hipStream_t stream) {
  const float* X  = (const float*)d_in[0];
  const float* Wq = (const float*)d_in[1];
  const float* Wk = (const float*)d_in[2];
  const float* Wv = (const float*)d_in[3];
  const float* Wo = (const float*)d_in[4];

  u16* wqb = (u16*)d_ws;                       // [4][1024][1024] bf16 (q,k,v,o)
  u16* wob = wqb + (size_t)3*D_MODEL*D_MODEL;
  u16* qkv = wqb + (size_t)4*D_MODEL*D_MODEL;  // [3][B*H][S][64]
  u16* att = qkv + (size_t)3*MTOT*D_MODEL;     // [8192][1024]

  (void)hipFuncSetAttribute((const void*)gemm_qkvf,
                            hipFuncAttributeMaxDynamicSharedMemorySize, 114688);
  (void)hipFuncSetAttribute((const void*)gemm_o8p,
                            hipFuncAttributeMaxDynamicSharedMemorySize, 98304);

  const int nw4 = D_MODEL*D_MODEL/4;
  dim3 gc(nw4/256, 4, 1);
  cvtk4<<<gc, 256, 0, stream>>>((const float4*)Wq, (const float4*)Wk,
                                (const float4*)Wv, (const float4*)Wo,
                                (u16x4*)wqb, nw4);

  gemm_qkvf<<<512, 512, 114688, stream>>>(X, wqb, qkv);

  attn6_k<<<256, 512, 0, stream>>>(qkv, qkv + (size_t)MTOT*D_MODEL,
                                   qkv + (size_t)2*MTOT*D_MODEL, att);

  gemm_o8p<<<256, 512, 98304, stream>>>(att, wob, (float*)d_out);
}

// Round 14
// 144.707 us; speedup vs baseline: 1.1797x; 1.1797x over previous
//
#include <hip/hip_runtime.h>
#include <stdint.h>

#define D_MODEL 1024
#define NHEADS  16
#define DHEAD   64
#define BATCH   4
#define SEQ     2048
#define MTOT    (BATCH*SEQ)

typedef unsigned short u16;
typedef uint32_t u32;
typedef __bf16 bf16x8 __attribute__((ext_vector_type(8)));
typedef float  f32x4  __attribute__((ext_vector_type(4)));
typedef float  f32x16 __attribute__((ext_vector_type(16)));
typedef u16    u16x8  __attribute__((ext_vector_type(8)));
typedef u16    u16x4  __attribute__((ext_vector_type(4)));
typedef u32    u32x4  __attribute__((ext_vector_type(4)));

__device__ __forceinline__ u16 f2bf(float f) {
  uint32_t u = __builtin_bit_cast(uint32_t, f);
  u += 0x7fff + ((u >> 16) & 1);   // RNE
  return (u16)(u >> 16);
}

__device__ __forceinline__ void gll16(const u16* g, u16* lds) {
  __builtin_amdgcn_global_load_lds(
      (__attribute__((address_space(1))) void*)(g),
      (__attribute__((address_space(3))) void*)(lds), 16, 0, 0);
}

// ---------------------------------------------------------------------------
// Single-launch fp32->bf16 convert for X + Wq + Wk + Wv + Wo (grid-stride).
// Output contiguous in d_ws: xb[2097152 x4] | wq | wk | wv | wo (x4 each).
// ---------------------------------------------------------------------------
#define NX4  2097152   // X float4 count
#define NW4  262144    // per-weight float4 count

__global__ void cvtall(const float4* __restrict__ X,  const float4* __restrict__ Wq,
                       const float4* __restrict__ Wk, const float4* __restrict__ Wv,
                       const float4* __restrict__ Wo, u16x4* __restrict__ out) {
  const int ntot = NX4 + 4*NW4;
  for (int i = blockIdx.x * blockDim.x + threadIdx.x; i < ntot;
       i += gridDim.x * blockDim.x) {
    float4 f;
    if (i < NX4) {
      f = X[i];
    } else {
      const int wi = i - NX4;
      const int s = wi >> 18;
      const int off = wi & (NW4 - 1);
      const float4* src = (s == 0) ? Wq : (s == 1) ? Wk : (s == 2) ? Wv : Wo;
      f = src[off];
    }
    u16x4 h;
    h[0] = f2bf(f.x); h[1] = f2bf(f.y); h[2] = f2bf(f.z); h[3] = f2bf(f.w);
    out[i] = h;
  }
}

#define QS 8192   // u16 per 16KB slot
#define BARS() __builtin_amdgcn_s_barrier()
#define LGKM0() do { asm volatile("s_waitcnt lgkmcnt(0)" ::: "memory"); \
                     __builtin_amdgcn_sched_barrier(0); } while (0)

// ---------------------------------------------------------------------------
// Fused QKV GEMM, BN=192 for PERFECT 2-round packing (512 blocks = 2x256).
// (byte-identical to R11's gemm_qkv192 — measured ~37us)
// ---------------------------------------------------------------------------
#define QP3 28672   // u16 per parity (56KB): A0 @0, A1 @8192, B @16384

#define Q3_ASTG(roff, t_, dstoff) do {                                            \
    gll16(pA + (size_t)(roff)*1024 + (t_)*64,      qsm + (dstoff) + w*512);       \
    gll16(pA + (size_t)((roff)+64)*1024 + (t_)*64, qsm + (dstoff) + w*512 + 4096);\
  } while (0)

#define Q3_BSTG(t_, dstoff) do {                                                  \
    gll16(pB + (size_t)0*1024  + (t_)*64, qsm + (dstoff) + w*1536);               \
    gll16(pB + (size_t)8*1024  + (t_)*64, qsm + (dstoff) + w*1536 + 512);         \
    gll16(pB + (size_t)16*1024 + (t_)*64, qsm + (dstoff) + w*1536 + 1024);        \
  } while (0)

#define Q3_READS_P1() do {                                                        \
    _Pragma("unroll")                                                             \
    for (int mf = 0; mf < 8; ++mf) {                                              \
      af0[mf] = *(const bf16x8*)&sA[(mf*16 + r15)*64 + cs0];                      \
      af1[mf] = *(const bf16x8*)&sA[(mf*16 + r15)*64 + cs1];                      \
    }                                                                             \
    _Pragma("unroll")                                                             \
    for (int nf = 0; nf < 3; ++nf)                                                \
      bq[nf] = *(const bf16x8*)&sB[(brow + nf*16 + r15)*64 + cs0];                \
  } while (0)

#define Q3_READS_P2() do {                                                        \
    _Pragma("unroll")                                                             \
    for (int nf = 0; nf < 3; ++nf)                                                \
      bq[nf] = *(const bf16x8*)&sB[(brow + nf*16 + r15)*64 + cs1];                \
  } while (0)

#define Q3_MM(AF) do {                                                            \
    __builtin_amdgcn_s_setprio(1);                                                \
    _Pragma("unroll")                                                             \
    for (int mf = 0; mf < 8; ++mf)                                                \
      _Pragma("unroll")                                                           \
      for (int nf = 0; nf < 3; ++nf)                                              \
        acc[mf][nf] = __builtin_amdgcn_mfma_f32_16x16x32_bf16(AF[mf], bq[nf],     \
                                                              acc[mf][nf], 0,0,0);\
    __builtin_amdgcn_s_setprio(0);                                                \
  } while (0)

__global__ __launch_bounds__(512, 2) void gemm_qkv192(
    const u16* __restrict__ A, const u16* __restrict__ Bw, u16* __restrict__ Out)
{
  extern __shared__ u16 qsm[];   // 112 KB
  const int tid = threadIdx.x;
  const int w = tid >> 6, l = tid & 63;
  const int wm = w >> 2, wn = w & 3;
  const int bid = blockIdx.x;
  const int wg = (bid & 7) * 64 + (bid >> 3);   // XCD-pinned (512 = 8*64)
  const int m0 = (wg >> 4) * 256, n0 = (wg & 15) * 192;

  // staging: lane row (l>>3), pre-swizzled source chunk
  const int sc8 = ((l & 7) ^ ((l >> 3) & 7)) * 8;
  const u16* pA = A  + (size_t)(m0 + 8*w  + (l >> 3)) * 1024 + sc8;
  const u16* pB = Bw + (size_t)(n0 + 24*w + (l >> 3)) * 1024 + sc8;

  const int r15 = l & 15;
  const int cs0 = (((l >> 4) + 0) ^ (l & 7)) * 8;
  const int cs1 = (((l >> 4) + 4) ^ (l & 7)) * 8;
  const int brow = wn * 48;

  f32x4 acc[8][3];
  #pragma unroll
  for (int i = 0; i < 8; ++i)
    #pragma unroll
    for (int j = 0; j < 3; ++j)
      acc[i][j] = f32x4{0.f, 0.f, 0.f, 0.f};

  // prologue: A0A1(0), B(0) [par0] + A0A1(1) [par1] = 11 loads
  Q3_ASTG(0,   0, 0);
  Q3_ASTG(128, 0, 8192);
  Q3_BSTG(0, 16384);
  Q3_ASTG(0,   1, QP3 + 0);
  Q3_ASTG(128, 1, QP3 + 8192);
  asm volatile("s_waitcnt vmcnt(4)" ::: "memory");   // tile0 complete
  BARS();
  __builtin_amdgcn_sched_barrier(0);

  #pragma unroll 2
  for (int t = 0; t < 14; ++t) {
    const int p = t & 1, po = p ^ 1;
    const u16* sA = qsm + (size_t)p*QP3 + (size_t)wm*8192;
    const u16* sB = qsm + (size_t)p*QP3 + 16384;
    bf16x8 af0[8], af1[8], bq[3];
    Q3_READS_P1();
    Q3_BSTG(t+1, po*QP3 + 16384);
    BARS(); LGKM0();
    Q3_MM(af0);
    BARS();
    Q3_READS_P2();
    Q3_ASTG(0,   t+2, p*QP3 + 0);
    Q3_ASTG(128, t+2, p*QP3 + 8192);
    BARS(); LGKM0();
    Q3_MM(af1);
    asm volatile("s_waitcnt vmcnt(4)" ::: "memory");  // tile t+1 complete
    BARS();
    __builtin_amdgcn_sched_barrier(0);
  }

  { // peeled t = 14 (p=0): p1 stages B(15); p2 no stage; drain
    const u16* sA = qsm + (size_t)wm*8192;
    const u16* sB = qsm + 16384;
    bf16x8 af0[8], af1[8], bq[3];
    Q3_READS_P1();
    Q3_BSTG(15, QP3 + 16384);
    BARS(); LGKM0();
    Q3_MM(af0);
    BARS();
    Q3_READS_P2();
    BARS(); LGKM0();
    Q3_MM(af1);
    asm volatile("s_waitcnt vmcnt(0)" ::: "memory");  // tile 15 complete
    BARS();
    __builtin_amdgcn_sched_barrier(0);
  }
  { // peeled t = 15 (p=1): plain compute
    const u16* sA = qsm + (size_t)QP3 + (size_t)wm*8192;
    const u16* sB = qsm + (size_t)QP3 + 16384;
    bf16x8 af0[8], af1[8], bq[3];
    Q3_READS_P1();
    Q3_MM(af0);
    Q3_READS_P2();
    Q3_MM(af1);
  }

  // epilogue: per-column z/scale, permuted bf16 store
  const float qs = 0.125f * 1.44269504088896f;
  const int g = l >> 4, c15 = l & 15;
  #pragma unroll
  for (int mf = 0; mf < 8; ++mf) {
    #pragma unroll
    for (int nf = 0; nf < 3; ++nf) {
      #pragma unroll
      for (int j = 0; j < 4; ++j) {
        const int row = m0 + wm*128 + mf*16 + g*4 + j;
        const int col = n0 + wn*48 + nf*16 + c15;
        const int z = col >> 10;
        const int wi = col & 1023;
        const float scale = (z == 0) ? qs : 1.0f;
        const int b = row >> 11, sq = row & (SEQ-1);
        const int h = wi >> 6, dh = wi & (DHEAD-1);
        Out[(size_t)z * MTOT * D_MODEL
            + ((size_t)(b*NHEADS + h) * SEQ + sq) * DHEAD + dh] =
            f2bf(acc[mf][nf][j] * scale);
      }
    }
  }
}

#undef Q3_ASTG
#undef Q3_BSTG
#undef Q3_READS_P1
#undef Q3_READS_P2
#undef Q3_MM

// ---------------------------------------------------------------------------
// Output projection GEMM (unchanged from R9): counted-vmcnt, 256 blocks.
// ---------------------------------------------------------------------------
#define OSTG(pbase, roff, t_, slot_) do {                                       \
    gll16((pbase) + (size_t)(roff)*1024 + (t_)*64,      osm + (slot_)*QS + w*512);        \
    gll16((pbase) + (size_t)((roff)+64)*1024 + (t_)*64, osm + (slot_)*QS + w*512 + 4096); \
  } while (0)

#define OREADS_P1() do {                                                        \
    _Pragma("unroll")                                                           \
    for (int mf = 0; mf < 8; ++mf) {                                            \
      af0[mf] = *(const bf16x8*)&sA[(mf*16 + r15)*64 + cs0];                    \
      af1[mf] = *(const bf16x8*)&sA[(mf*16 + r15)*64 + cs1];                    \
    }                                                                           \
    _Pragma("unroll")                                                           \
    for (int nf = 0; nf < 2; ++nf)                                              \
      bq[nf] = *(const bf16x8*)&sB[(brow + nf*16 + r15)*64 + cs0];              \
  } while (0)

#define OREADS_P2() do {                                                        \
    _Pragma("unroll")                                                           \
    for (int nf = 0; nf < 2; ++nf)                                              \
      bq[nf] = *(const bf16x8*)&sB[(brow + nf*16 + r15)*64 + cs1];              \
  } while (0)

#define OMM(AF) do {                                                            \
    __builtin_amdgcn_s_setprio(1);                                              \
    _Pragma("unroll")                                                           \
    for (int mf = 0; mf < 8; ++mf) {                                            \
      acc[mf][0] = __builtin_amdgcn_mfma_f32_16x16x32_bf16(AF[mf], bq[0],       \
                                                           acc[mf][0], 0,0,0);  \
      acc[mf][1] = __builtin_amdgcn_mfma_f32_16x16x32_bf16(AF[mf], bq[1],       \
                                                           acc[mf][1], 0,0,0);  \
    }                                                                           \
    __builtin_amdgcn_s_setprio(0);                                              \
  } while (0)

__global__ __launch_bounds__(512, 2) void gemm_o8p(
    const u16* __restrict__ A, const u16* __restrict__ Bw, float* __restrict__ Out)
{
  extern __shared__ u16 osm[];   // 6 * 16KB = 96KB
  const int tid = threadIdx.x;
  const int w = tid >> 6, l = tid & 63;
  const int wm = w >> 2, wn = w & 3;
  const int bid = blockIdx.x;
  const int wg = (bid & 7) * 32 + (bid >> 3);   // XCD-pinned (256 = 8*32)
  const int m0 = (wg >> 3) * 256, n0 = (wg & 7) * 128;

  const int sr  = 8*w + (l >> 3);
  const int sc8 = ((l & 7) ^ ((l >> 3) & 7)) * 8;
  const u16* pA = A  + (size_t)(m0 + sr) * 1024 + sc8;
  const u16* pB = Bw + (size_t)(n0 + sr) * 1024 + sc8;

  const int r15 = l & 15;
  const int cs0 = (((l >> 4) + 0) ^ (l & 7)) * 8;
  const int cs1 = (((l >> 4) + 4) ^ (l & 7)) * 8;
  const int brow = wn * 32;

  f32x4 acc[8][2];
  #pragma unroll
  for (int i = 0; i < 8; ++i) {
    acc[i][0] = f32x4{0.f, 0.f, 0.f, 0.f};
    acc[i][1] = f32x4{0.f, 0.f, 0.f, 0.f};
  }

  OSTG(pA, 0,   0, 0);
  OSTG(pA, 128, 0, 1);
  OSTG(pB, 0,   0, 2);
  OSTG(pA, 0,   1, 3);
  OSTG(pA, 128, 1, 4);
  asm volatile("s_waitcnt vmcnt(4)" ::: "memory");
  BARS();
  __builtin_amdgcn_sched_barrier(0);

  #pragma unroll 2
  for (int t = 0; t < 14; ++t) {
    const int p = t & 1, po = p ^ 1;
    const u16* sA = osm + (size_t)(p*3 + wm) * QS;
    const u16* sB = osm + (size_t)(p*3 + 2) * QS;
    bf16x8 af0[8], af1[8], bq[2];
    OREADS_P1();
    OSTG(pB, 0, t+1, po*3 + 2);
    BARS(); LGKM0();
    OMM(af0);
    BARS();
    OREADS_P2();
    OSTG(pA, 0,   t+2, p*3 + 0);
    OSTG(pA, 128, t+2, p*3 + 1);
    BARS(); LGKM0();
    OMM(af1);
    asm volatile("s_waitcnt vmcnt(4)" ::: "memory");
    BARS();
    __builtin_amdgcn_sched_barrier(0);
  }

  {
    const u16* sA = osm + (size_t)(0*3 + wm) * QS;
    const u16* sB = osm + (size_t)(0*3 + 2) * QS;
    bf16x8 af0[8], af1[8], bq[2];
    OREADS_P1();
    OSTG(pB, 0, 15, 1*3 + 2);
    BARS(); LGKM0();
    OMM(af0);
    BARS();
    OREADS_P2();
    BARS(); LGKM0();
    OMM(af1);
    asm volatile("s_waitcnt vmcnt(0)" ::: "memory");
    BARS();
    __builtin_amdgcn_sched_barrier(0);
  }
  {
    const u16* sA = osm + (size_t)(1*3 + wm) * QS;
    const u16* sB = osm + (size_t)(1*3 + 2) * QS;
    bf16x8 af0[8], af1[8], bq[2];
    OREADS_P1();
    OMM(af0);
    OREADS_P2();
    OMM(af1);
  }

  const int g = l >> 4, c15 = l & 15;
  #pragma unroll
  for (int mf = 0; mf < 8; ++mf) {
    #pragma unroll
    for (int nf = 0; nf < 2; ++nf) {
      #pragma unroll
      for (int j = 0; j < 4; ++j) {
        const int row = m0 + wm*128 + mf*16 + g*4 + j;
        const int col = n0 + wn*32 + nf*16 + c15;
        Out[(size_t)row * D_MODEL + col] = acc[mf][nf][j];
      }
    }
  }
}

#undef OSTG
#undef OREADS_P1
#undef OREADS_P2
#undef OMM

// ---------------------------------------------------------------------------
// Causal flash attention (attn6, best-measured 69.3us — byte-identical):
// 8 warps x 32 q-rows, KVBLK=128, paired superblocks {p, 7-p}, grid 256,
// 32x32x16 MFMA, O^T form, T13 defer-max, swizzled K/V LDS.
// ---------------------------------------------------------------------------
__launch_bounds__(512, 2)
__global__ void attn6_k(const u16* __restrict__ Qb, const u16* __restrict__ Kb_,
                        const u16* __restrict__ Vb_, u16* __restrict__ Oa)
{
  const int tid = threadIdx.x;
  const int w = tid >> 6, l = tid & 63;
  const int q5 = l & 31, hi = l >> 5;
  const int r = blockIdx.x;
  const int bh = (r & 7) * 8 + ((r >> 3) & 7);
  const int pairi = r >> 6;                     // 0..3
  const int b = bh >> 4, h = bh & 15;
  const size_t base = (size_t)bh * SEQ * DHEAD;
  const u16* Qg = Qb + base;
  const u16* Kg = Kb_ + base;
  const u16* Vg = Vb_ + base;

  __shared__ __align__(16) u16 smem[32768];

  const int kc = tid & 7, rp = tid >> 3;
  const int vsub = rp >> 5;
  const int rp5 = rp & 31;
  int vIdx32[8];
  #pragma unroll
  for (int e = 0; e < 8; ++e)
    vIdx32[e] = vsub*2048 + (8*kc + e)*32 + ((((rp5 >> 2) ^ kc ^ e) & 7) << 2) + (rp5 & 3);

  const int kr8 = l >> 3;
  const int kkv = 8*w + kr8;
  const int kdc = (l & 7) ^ kr8 ^ w;

  for (int half = 0; half < 2; ++half) {
    const int tq = half ? (7 - pairi) : pairi;
    const int q0w = tq*256 + 32*w;
    const int ntk = (tq + 1) * 2;
    const int ntw = (q0w >> 7) + 1;

    bf16x8 qf[4];
    #pragma unroll
    for (int s = 0; s < 4; ++s)
      qf[s] = *(const bf16x8*)(Qg + (size_t)(q0w + q5)*DHEAD + 16*s + 8*hi);

    f32x16 c0 = {}, c1 = {};
    float mrun = -1e30f, lrun = 0.f;

    {
      #pragma unroll
      for (int h2 = 0; h2 < 2; ++h2)
        gll16(Kg + (size_t)(64*h2 + kkv)*DHEAD + kdc*8, smem + h2*4096 + w*512);
      const u16x8 v0 = *(const u16x8*)(Vg + (size_t)(2*rp)*DHEAD + kc*8);
      const u16x8 v1 = *(const u16x8*)(Vg + (size_t)(2*rp + 1)*DHEAD + kc*8);
      u32* Vd = (u32*)(smem + 16384);
      #pragma unroll
      for (int e = 0; e < 8; ++e)
        Vd[vIdx32[e]] = (u32)v0[e] | ((u32)v1[e] << 16);
    }
    __syncthreads();

    for (int t = 0; t < ntk; ++t) {
      const int cur = t & 1;
      const bool pf = (t + 1 < ntk);
      u16x8 v0, v1;
      if (pf) {
        const int kv1 = (t + 1) * 128;
        v0 = *(const u16x8*)(Vg + (size_t)(kv1 + 2*rp)*DHEAD + kc*8);
        v1 = *(const u16x8*)(Vg + (size_t)(kv1 + 2*rp + 1)*DHEAD + kc*8);
        #pragma unroll
        for (int h2 = 0; h2 < 2; ++h2)
          gll16(Kg + (size_t)(kv1 + 64*h2 + kkv)*DHEAD + kdc*8,
                smem + (cur^1)*8192 + h2*4096 + w*512);
      }

      if (t < ntw) {
        const u16* Kb = smem + cur*8192;
        const u16* Vv = smem + 16384 + cur*8192;

        f32x16 st[4] = {{}, {}, {}, {}};
        __builtin_amdgcn_s_setprio(1);
        #pragma unroll
        for (int kbg = 0; kbg < 4; ++kbg) {
          #pragma unroll
          for (int s = 0; s < 4; ++s) {
            const int slot = ((2*s + hi) ^ (l & 7) ^ ((4*(kbg & 1)) & 7) ^ (q5 >> 3)) & 7;
            const bf16x8 kf = *(const bf16x8*)(Kb + (kbg >> 1)*4096
                                               + ((kbg & 1)*32 + q5)*64 + slot*8);
            st[kbg] = __builtin_amdgcn_mfma_f32_32x32x16_bf16(kf, qf[s], st[kbg], 0, 0, 0);
          }
        }
        __builtin_amdgcn_s_setprio(0);

        if (t == ntw - 1) {
          const int kv0 = t * 128;
          #pragma unroll
          for (int kbg = 0; kbg < 4; ++kbg)
            #pragma unroll
            for (int rr = 0; rr < 16; ++rr) {
              const int kvg = kv0 + 32*kbg + (rr & 3) + 8*(rr >> 2) + 4*hi;
              if (kvg > q0w + q5) st[kbg][rr] = -1e30f;
            }
        }

        float mx = -1e30f;
        #pragma unroll
        for (int kbg = 0; kbg < 4; ++kbg)
          #pragma unroll
          for (int rr = 0; rr < 16; ++rr) mx = fmaxf(mx, st[kbg][rr]);
        mx = fmaxf(mx, __shfl_xor(mx, 32));
        float alpha = 1.0f;
        if (!__all(mx <= mrun + 8.0f)) {
          const float mnew = fmaxf(mrun, mx);
          alpha = __builtin_amdgcn_exp2f(mrun - mnew);
          mrun = mnew;
          #pragma unroll
          for (int rr = 0; rr < 16; ++rr) { c0[rr] *= alpha; c1[rr] *= alpha; }
        }
        float rs = 0.f;
        #pragma unroll
        for (int kbg = 0; kbg < 4; ++kbg)
          #pragma unroll
          for (int rr = 0; rr < 16; ++rr) {
            const float pe = __builtin_amdgcn_exp2f(st[kbg][rr] - mrun);
            st[kbg][rr] = pe;
            rs += pe;
          }
        rs += __shfl_xor(rs, 32);
        lrun = lrun * alpha + rs;

        bf16x8 pb[8];
        #pragma unroll
        for (int kbg = 0; kbg < 4; ++kbg) {
          u32 pw[8];
          #pragma unroll
          for (int i = 0; i < 8; ++i) {
            u32 t0;
            asm("v_cvt_pk_bf16_f32 %0, %1, %2"
                : "=v"(t0) : "v"(st[kbg][2*i]), "v"(st[kbg][2*i+1]));
            pw[i] = t0;
          }
          asm("v_permlane32_swap_b32 %0, %1" : "+v"(pw[0]), "+v"(pw[2]));
          asm("v_permlane32_swap_b32 %0, %1" : "+v"(pw[1]), "+v"(pw[3]));
          asm("v_permlane32_swap_b32 %0, %1" : "+v"(pw[4]), "+v"(pw[6]));
          asm("v_permlane32_swap_b32 %0, %1" : "+v"(pw[5]), "+v"(pw[7]));
          pb[2*kbg]   = __builtin_bit_cast(bf16x8, u32x4{pw[0], pw[1], pw[2], pw[3]});
          pb[2*kbg+1] = __builtin_bit_cast(bf16x8, u32x4{pw[4], pw[5], pw[6], pw[7]});
        }

        __builtin_amdgcn_s_setprio(1);
        #pragma unroll
        for (int h2 = 0; h2 < 2; ++h2) {
          #pragma unroll
          for (int s = 0; s < 4; ++s) {
            {
              const int slot = ((2*s + hi) ^ (l & 7) ^ (q5 >> 3)) & 7;
              const bf16x8 vf = *(const bf16x8*)(Vv + h2*4096 + q5*64 + slot*8);
              c0 = __builtin_amdgcn_mfma_f32_32x32x16_bf16(vf, pb[4*h2 + s], c0, 0, 0, 0);
            }
            {
              const int slot = ((2*s + hi) ^ (l & 7) ^ 4 ^ (q5 >> 3)) & 7;
              const bf16x8 vf = *(const bf16x8*)(Vv + h2*4096 + (32 + q5)*64 + slot*8);
              c1 = __builtin_amdgcn_mfma_f32_32x32x16_bf16(vf, pb[4*h2 + s], c1, 0, 0, 0);
            }
          }
        }
        __builtin_amdgcn_s_setprio(0);
      }

      if (pf) {
        u32* Vd = (u32*)(smem + 16384) + (cur^1)*4096;
        #pragma unroll
        for (int e = 0; e < 8; ++e)
          Vd[vIdx32[e]] = (u32)v0[e] | ((u32)v1[e] << 16);
      }
      __syncthreads();
    }

    const float linv = __builtin_amdgcn_rcpf(lrun);
    #pragma unroll
    for (int Ab = 0; Ab < 2; ++Ab)
      #pragma unroll
      for (int rr = 0; rr < 16; ++rr) {
        const int d = 32*Ab + (rr & 3) + 8*(rr >> 2) + 4*hi;
        smem[w*2048 + q5*64 + (((d >> 3) ^ (q5 & 7)) & 7)*8 + (d & 7)] =
            f2bf((Ab ? c1[rr] : c0[rr]) * linv);
      }
    __syncthreads();
    #pragma unroll
    for (int cc = 0; cc < 4; ++cc) {
      const int dchunk = 4*hi + cc;
      const u16x8 vv = *(const u16x8*)&smem[w*2048 + q5*64 + ((dchunk ^ (q5 & 7)) & 7)*8];
      *(u16x8*)(Oa + (size_t)(b*SEQ + q0w + q5)*D_MODEL + h*DHEAD + 32*hi + 8*cc) = vv;
    }
    __syncthreads();
  }
}

extern "C" void kernel_launch(void* const* d_in, const int* in_sizes, int n_in,
                              void* d_out, int out_size, void* d_ws, size_t ws_size,
                              hipStream_t stream) {
  const float* X  = (const float*)d_in[0];
  const float* Wq = (const float*)d_in[1];
  const float* Wk = (const float*)d_in[2];
  const float* Wv = (const float*)d_in[3];
  const float* Wo = (const float*)d_in[4];

  u16* xb  = (u16*)d_ws;
  u16* wqb = xb  + (size_t)MTOT*D_MODEL;
  u16* wob = wqb + (size_t)3*D_MODEL*D_MODEL;
  u16* qkv = wob + (size_t)D_MODEL*D_MODEL;   // [3][B*H][S][64]
  u16* att = qkv + (size_t)3*MTOT*D_MODEL;    // [8192][1024]

  (void)hipFuncSetAttribute((const void*)gemm_qkv192,
                            hipFuncAttributeMaxDynamicSharedMemorySize, 114688);
  (void)hipFuncSetAttribute((const void*)gemm_o8p,
                            hipFuncAttributeMaxDynamicSharedMemorySize, 98304);

  cvtall<<<2048, 256, 0, stream>>>((const float4*)X,  (const float4*)Wq,
                                   (const float4*)Wk, (const float4*)Wv,
                                   (const float4*)Wo, (u16x4*)xb);

  gemm_qkv192<<<512, 512, 114688, stream>>>(xb, wqb, qkv);

  attn6_k<<<256, 512, 0, stream>>>(qkv, qkv + (size_t)MTOT*D_MODEL,
                                   qkv + (size_t)2*MTOT*D_MODEL, att);

  gemm_o8p<<<256, 512, 98304, stream>>>(att, wob, (float*)d_out);
}

// Round 15
// 139.636 us; speedup vs baseline: 1.2225x; 1.0363x over previous
//
#include <hip/hip_runtime.h>
#include <stdint.h>

#define D_MODEL 1024
#define NHEADS  16
#define DHEAD   64
#define BATCH   4
#define SEQ     2048
#define MTOT    (BATCH*SEQ)

typedef unsigned short u16;
typedef uint32_t u32;
typedef __bf16 bf16x8 __attribute__((ext_vector_type(8)));
typedef float  f32x4  __attribute__((ext_vector_type(4)));
typedef float  f32x16 __attribute__((ext_vector_type(16)));
typedef u16    u16x8  __attribute__((ext_vector_type(8)));
typedef u16    u16x4  __attribute__((ext_vector_type(4)));
typedef u32    u32x4  __attribute__((ext_vector_type(4)));

__device__ __forceinline__ u16 f2bf(float f) {
  uint32_t u = __builtin_bit_cast(uint32_t, f);
  u += 0x7fff + ((u >> 16) & 1);   // RNE
  return (u16)(u >> 16);
}

__device__ __forceinline__ void gll16(const u16* g, u16* lds) {
  __builtin_amdgcn_global_load_lds(
      (__attribute__((address_space(1))) void*)(g),
      (__attribute__((address_space(3))) void*)(lds), 16, 0, 0);
}

// ---------------------------------------------------------------------------
// Single-launch fp32->bf16 convert for X + Wq + Wk + Wv + Wo (grid-stride).
// ---------------------------------------------------------------------------
#define NX4  2097152   // X float4 count
#define NW4  262144    // per-weight float4 count

__global__ void cvtall(const float4* __restrict__ X,  const float4* __restrict__ Wq,
                       const float4* __restrict__ Wk, const float4* __restrict__ Wv,
                       const float4* __restrict__ Wo, u16x4* __restrict__ out) {
  const int ntot = NX4 + 4*NW4;
  for (int i = blockIdx.x * blockDim.x + threadIdx.x; i < ntot;
       i += gridDim.x * blockDim.x) {
    float4 f;
    if (i < NX4) {
      f = X[i];
    } else {
      const int wi = i - NX4;
      const int s = wi >> 18;
      const int off = wi & (NW4 - 1);
      const float4* src = (s == 0) ? Wq : (s == 1) ? Wk : (s == 2) ? Wv : Wo;
      f = src[off];
    }
    u16x4 h;
    h[0] = f2bf(f.x); h[1] = f2bf(f.y); h[2] = f2bf(f.z); h[3] = f2bf(f.w);
    out[i] = h;
  }
}

#define QS 8192   // u16 per 16KB slot
#define BARS() __builtin_amdgcn_s_barrier()
#define LGKM0() do { asm volatile("s_waitcnt lgkmcnt(0)" ::: "memory"); \
                     __builtin_amdgcn_sched_barrier(0); } while (0)

// ---------------------------------------------------------------------------
// Fused QKV GEMM, BN=192 2-round packing (byte-identical to R11, ~37us).
// ---------------------------------------------------------------------------
#define QP3 28672   // u16 per parity (56KB): A0 @0, A1 @8192, B @16384

#define Q3_ASTG(roff, t_, dstoff) do {                                            \
    gll16(pA + (size_t)(roff)*1024 + (t_)*64,      qsm + (dstoff) + w*512);       \
    gll16(pA + (size_t)((roff)+64)*1024 + (t_)*64, qsm + (dstoff) + w*512 + 4096);\
  } while (0)

#define Q3_BSTG(t_, dstoff) do {                                                  \
    gll16(pB + (size_t)0*1024  + (t_)*64, qsm + (dstoff) + w*1536);               \
    gll16(pB + (size_t)8*1024  + (t_)*64, qsm + (dstoff) + w*1536 + 512);         \
    gll16(pB + (size_t)16*1024 + (t_)*64, qsm + (dstoff) + w*1536 + 1024);        \
  } while (0)

#define Q3_READS_P1() do {                                                        \
    _Pragma("unroll")                                                             \
    for (int mf = 0; mf < 8; ++mf) {                                              \
      af0[mf] = *(const bf16x8*)&sA[(mf*16 + r15)*64 + cs0];                      \
      af1[mf] = *(const bf16x8*)&sA[(mf*16 + r15)*64 + cs1];                      \
    }                                                                             \
    _Pragma("unroll")                                                             \
    for (int nf = 0; nf < 3; ++nf)                                                \
      bq[nf] = *(const bf16x8*)&sB[(brow + nf*16 + r15)*64 + cs0];                \
  } while (0)

#define Q3_READS_P2() do {                                                        \
    _Pragma("unroll")                                                             \
    for (int nf = 0; nf < 3; ++nf)                                                \
      bq[nf] = *(const bf16x8*)&sB[(brow + nf*16 + r15)*64 + cs1];                \
  } while (0)

#define Q3_MM(AF) do {                                                            \
    __builtin_amdgcn_s_setprio(1);                                                \
    _Pragma("unroll")                                                             \
    for (int mf = 0; mf < 8; ++mf)                                                \
      _Pragma("unroll")                                                           \
      for (int nf = 0; nf < 3; ++nf)                                              \
        acc[mf][nf] = __builtin_amdgcn_mfma_f32_16x16x32_bf16(AF[mf], bq[nf],     \
                                                              acc[mf][nf], 0,0,0);\
    __builtin_amdgcn_s_setprio(0);                                                \
  } while (0)

__global__ __launch_bounds__(512, 2) void gemm_qkv192(
    const u16* __restrict__ A, const u16* __restrict__ Bw, u16* __restrict__ Out)
{
  extern __shared__ u16 qsm[];   // 112 KB
  const int tid = threadIdx.x;
  const int w = tid >> 6, l = tid & 63;
  const int wm = w >> 2, wn = w & 3;
  const int bid = blockIdx.x;
  const int wg = (bid & 7) * 64 + (bid >> 3);   // XCD-pinned (512 = 8*64)
  const int m0 = (wg >> 4) * 256, n0 = (wg & 15) * 192;

  const int sc8 = ((l & 7) ^ ((l >> 3) & 7)) * 8;
  const u16* pA = A  + (size_t)(m0 + 8*w  + (l >> 3)) * 1024 + sc8;
  const u16* pB = Bw + (size_t)(n0 + 24*w + (l >> 3)) * 1024 + sc8;

  const int r15 = l & 15;
  const int cs0 = (((l >> 4) + 0) ^ (l & 7)) * 8;
  const int cs1 = (((l >> 4) + 4) ^ (l & 7)) * 8;
  const int brow = wn * 48;

  f32x4 acc[8][3];
  #pragma unroll
  for (int i = 0; i < 8; ++i)
    #pragma unroll
    for (int j = 0; j < 3; ++j)
      acc[i][j] = f32x4{0.f, 0.f, 0.f, 0.f};

  Q3_ASTG(0,   0, 0);
  Q3_ASTG(128, 0, 8192);
  Q3_BSTG(0, 16384);
  Q3_ASTG(0,   1, QP3 + 0);
  Q3_ASTG(128, 1, QP3 + 8192);
  asm volatile("s_waitcnt vmcnt(4)" ::: "memory");   // tile0 complete
  BARS();
  __builtin_amdgcn_sched_barrier(0);

  #pragma unroll 2
  for (int t = 0; t < 14; ++t) {
    const int p = t & 1, po = p ^ 1;
    const u16* sA = qsm + (size_t)p*QP3 + (size_t)wm*8192;
    const u16* sB = qsm + (size_t)p*QP3 + 16384;
    bf16x8 af0[8], af1[8], bq[3];
    Q3_READS_P1();
    Q3_BSTG(t+1, po*QP3 + 16384);
    BARS(); LGKM0();
    Q3_MM(af0);
    BARS();
    Q3_READS_P2();
    Q3_ASTG(0,   t+2, p*QP3 + 0);
    Q3_ASTG(128, t+2, p*QP3 + 8192);
    BARS(); LGKM0();
    Q3_MM(af1);
    asm volatile("s_waitcnt vmcnt(4)" ::: "memory");  // tile t+1 complete
    BARS();
    __builtin_amdgcn_sched_barrier(0);
  }

  {
    const u16* sA = qsm + (size_t)wm*8192;
    const u16* sB = qsm + 16384;
    bf16x8 af0[8], af1[8], bq[3];
    Q3_READS_P1();
    Q3_BSTG(15, QP3 + 16384);
    BARS(); LGKM0();
    Q3_MM(af0);
    BARS();
    Q3_READS_P2();
    BARS(); LGKM0();
    Q3_MM(af1);
    asm volatile("s_waitcnt vmcnt(0)" ::: "memory");  // tile 15 complete
    BARS();
    __builtin_amdgcn_sched_barrier(0);
  }
  {
    const u16* sA = qsm + (size_t)QP3 + (size_t)wm*8192;
    const u16* sB = qsm + (size_t)QP3 + 16384;
    bf16x8 af0[8], af1[8], bq[3];
    Q3_READS_P1();
    Q3_MM(af0);
    Q3_READS_P2();
    Q3_MM(af1);
  }

  const float qs = 0.125f * 1.44269504088896f;
  const int g = l >> 4, c15 = l & 15;
  #pragma unroll
  for (int mf = 0; mf < 8; ++mf) {
    #pragma unroll
    for (int nf = 0; nf < 3; ++nf) {
      #pragma unroll
      for (int j = 0; j < 4; ++j) {
        const int row = m0 + wm*128 + mf*16 + g*4 + j;
        const int col = n0 + wn*48 + nf*16 + c15;
        const int z = col >> 10;
        const int wi = col & 1023;
        const float scale = (z == 0) ? qs : 1.0f;
        const int b = row >> 11, sq = row & (SEQ-1);
        const int h = wi >> 6, dh = wi & (DHEAD-1);
        Out[(size_t)z * MTOT * D_MODEL
            + ((size_t)(b*NHEADS + h) * SEQ + sq) * DHEAD + dh] =
            f2bf(acc[mf][nf][j] * scale);
      }
    }
  }
}

#undef Q3_ASTG
#undef Q3_BSTG
#undef Q3_READS_P1
#undef Q3_READS_P2
#undef Q3_MM

// ---------------------------------------------------------------------------
// Output projection GEMM (byte-identical to R9): counted-vmcnt, 256 blocks.
// ---------------------------------------------------------------------------
#define OSTG(pbase, roff, t_, slot_) do {                                       \
    gll16((pbase) + (size_t)(roff)*1024 + (t_)*64,      osm + (slot_)*QS + w*512);        \
    gll16((pbase) + (size_t)((roff)+64)*1024 + (t_)*64, osm + (slot_)*QS + w*512 + 4096); \
  } while (0)

#define OREADS_P1() do {                                                        \
    _Pragma("unroll")                                                           \
    for (int mf = 0; mf < 8; ++mf) {                                            \
      af0[mf] = *(const bf16x8*)&sA[(mf*16 + r15)*64 + cs0];                    \
      af1[mf] = *(const bf16x8*)&sA[(mf*16 + r15)*64 + cs1];                    \
    }                                                                           \
    _Pragma("unroll")                                                           \
    for (int nf = 0; nf < 2; ++nf)                                              \
      bq[nf] = *(const bf16x8*)&sB[(brow + nf*16 + r15)*64 + cs0];              \
  } while (0)

#define OREADS_P2() do {                                                        \
    _Pragma("unroll")                                                           \
    for (int nf = 0; nf < 2; ++nf)                                              \
      bq[nf] = *(const bf16x8*)&sB[(brow + nf*16 + r15)*64 + cs1];              \
  } while (0)

#define OMM(AF) do {                                                            \
    __builtin_amdgcn_s_setprio(1);                                              \
    _Pragma("unroll")                                                           \
    for (int mf = 0; mf < 8; ++mf) {                                            \
      acc[mf][0] = __builtin_amdgcn_mfma_f32_16x16x32_bf16(AF[mf], bq[0],       \
                                                           acc[mf][0], 0,0,0);  \
      acc[mf][1] = __builtin_amdgcn_mfma_f32_16x16x32_bf16(AF[mf], bq[1],       \
                                                           acc[mf][1], 0,0,0);  \
    }                                                                           \
    __builtin_amdgcn_s_setprio(0);                                              \
  } while (0)

__global__ __launch_bounds__(512, 2) void gemm_o8p(
    const u16* __restrict__ A, const u16* __restrict__ Bw, float* __restrict__ Out)
{
  extern __shared__ u16 osm[];   // 6 * 16KB = 96KB
  const int tid = threadIdx.x;
  const int w = tid >> 6, l = tid & 63;
  const int wm = w >> 2, wn = w & 3;
  const int bid = blockIdx.x;
  const int wg = (bid & 7) * 32 + (bid >> 3);   // XCD-pinned (256 = 8*32)
  const int m0 = (wg >> 3) * 256, n0 = (wg & 7) * 128;

  const int sr  = 8*w + (l >> 3);
  const int sc8 = ((l & 7) ^ ((l >> 3) & 7)) * 8;
  const u16* pA = A  + (size_t)(m0 + sr) * 1024 + sc8;
  const u16* pB = Bw + (size_t)(n0 + sr) * 1024 + sc8;

  const int r15 = l & 15;
  const int cs0 = (((l >> 4) + 0) ^ (l & 7)) * 8;
  const int cs1 = (((l >> 4) + 4) ^ (l & 7)) * 8;
  const int brow = wn * 32;

  f32x4 acc[8][2];
  #pragma unroll
  for (int i = 0; i < 8; ++i) {
    acc[i][0] = f32x4{0.f, 0.f, 0.f, 0.f};
    acc[i][1] = f32x4{0.f, 0.f, 0.f, 0.f};
  }

  OSTG(pA, 0,   0, 0);
  OSTG(pA, 128, 0, 1);
  OSTG(pB, 0,   0, 2);
  OSTG(pA, 0,   1, 3);
  OSTG(pA, 128, 1, 4);
  asm volatile("s_waitcnt vmcnt(4)" ::: "memory");
  BARS();
  __builtin_amdgcn_sched_barrier(0);

  #pragma unroll 2
  for (int t = 0; t < 14; ++t) {
    const int p = t & 1, po = p ^ 1;
    const u16* sA = osm + (size_t)(p*3 + wm) * QS;
    const u16* sB = osm + (size_t)(p*3 + 2) * QS;
    bf16x8 af0[8], af1[8], bq[2];
    OREADS_P1();
    OSTG(pB, 0, t+1, po*3 + 2);
    BARS(); LGKM0();
    OMM(af0);
    BARS();
    OREADS_P2();
    OSTG(pA, 0,   t+2, p*3 + 0);
    OSTG(pA, 128, t+2, p*3 + 1);
    BARS(); LGKM0();
    OMM(af1);
    asm volatile("s_waitcnt vmcnt(4)" ::: "memory");
    BARS();
    __builtin_amdgcn_sched_barrier(0);
  }

  {
    const u16* sA = osm + (size_t)(0*3 + wm) * QS;
    const u16* sB = osm + (size_t)(0*3 + 2) * QS;
    bf16x8 af0[8], af1[8], bq[2];
    OREADS_P1();
    OSTG(pB, 0, 15, 1*3 + 2);
    BARS(); LGKM0();
    OMM(af0);
    BARS();
    OREADS_P2();
    BARS(); LGKM0();
    OMM(af1);
    asm volatile("s_waitcnt vmcnt(0)" ::: "memory");
    BARS();
    __builtin_amdgcn_sched_barrier(0);
  }
  {
    const u16* sA = osm + (size_t)(1*3 + wm) * QS;
    const u16* sB = osm + (size_t)(1*3 + 2) * QS;
    bf16x8 af0[8], af1[8], bq[2];
    OREADS_P1();
    OMM(af0);
    OREADS_P2();
    OMM(af1);
  }

  const int g = l >> 4, c15 = l & 15;
  #pragma unroll
  for (int mf = 0; mf < 8; ++mf) {
    #pragma unroll
    for (int nf = 0; nf < 2; ++nf) {
      #pragma unroll
      for (int j = 0; j < 4; ++j) {
        const int row = m0 + wm*128 + mf*16 + g*4 + j;
        const int col = n0 + wn*32 + nf*16 + c15;
        Out[(size_t)row * D_MODEL + col] = acc[mf][nf][j];
      }
    }
  }
}

#undef OSTG
#undef OREADS_P1
#undef OREADS_P2
#undef OMM

// ---------------------------------------------------------------------------
// Causal flash attention v9: attn6 with INTERLEAVED softmax/PV sub-tiles.
// Pure instruction reorder (same ops, sync, buffers): PV(h2=0) needs only
// pb[0..3] = softmax slices kbg0,1 -> order is now
//   QK(all) -> mask -> max/defer/rescale (whole tile) ->
//   exp+pack kbg0,1 -> PV(h2=0) -> exp+pack kbg2,3 -> PV(h2=1)
// so slice-B's exp2 (trans pipe) can issue under PV(h2=0)'s MFMA cluster.
// ---------------------------------------------------------------------------
__launch_bounds__(512, 2)
__global__ void attn9_k(const u16* __restrict__ Qb, const u16* __restrict__ Kb_,
                        const u16* __restrict__ Vb_, u16* __restrict__ Oa)
{
  const int tid = threadIdx.x;
  const int w = tid >> 6, l = tid & 63;
  const int q5 = l & 31, hi = l >> 5;
  const int r = blockIdx.x;
  const int bh = (r & 7) * 8 + ((r >> 3) & 7);
  const int pairi = r >> 6;                     // 0..3
  const int b = bh >> 4, h = bh & 15;
  const size_t base = (size_t)bh * SEQ * DHEAD;
  const u16* Qg = Qb + base;
  const u16* Kg = Kb_ + base;
  const u16* Vg = Vb_ + base;

  __shared__ __align__(16) u16 smem[32768];

  const int kc = tid & 7, rp = tid >> 3;
  const int vsub = rp >> 5;
  const int rp5 = rp & 31;
  int vIdx32[8];
  #pragma unroll
  for (int e = 0; e < 8; ++e)
    vIdx32[e] = vsub*2048 + (8*kc + e)*32 + ((((rp5 >> 2) ^ kc ^ e) & 7) << 2) + (rp5 & 3);

  const int kr8 = l >> 3;
  const int kkv = 8*w + kr8;
  const int kdc = (l & 7) ^ kr8 ^ w;

  for (int half = 0; half < 2; ++half) {
    const int tq = half ? (7 - pairi) : pairi;
    const int q0w = tq*256 + 32*w;
    const int ntk = (tq + 1) * 2;
    const int ntw = (q0w >> 7) + 1;

    bf16x8 qf[4];
    #pragma unroll
    for (int s = 0; s < 4; ++s)
      qf[s] = *(const bf16x8*)(Qg + (size_t)(q0w + q5)*DHEAD + 16*s + 8*hi);

    f32x16 c0 = {}, c1 = {};
    float mrun = -1e30f, lrun = 0.f;

    {
      #pragma unroll
      for (int h2 = 0; h2 < 2; ++h2)
        gll16(Kg + (size_t)(64*h2 + kkv)*DHEAD + kdc*8, smem + h2*4096 + w*512);
      const u16x8 v0 = *(const u16x8*)(Vg + (size_t)(2*rp)*DHEAD + kc*8);
      const u16x8 v1 = *(const u16x8*)(Vg + (size_t)(2*rp + 1)*DHEAD + kc*8);
      u32* Vd = (u32*)(smem + 16384);
      #pragma unroll
      for (int e = 0; e < 8; ++e)
        Vd[vIdx32[e]] = (u32)v0[e] | ((u32)v1[e] << 16);
    }
    __syncthreads();

    for (int t = 0; t < ntk; ++t) {
      const int cur = t & 1;
      const bool pf = (t + 1 < ntk);
      u16x8 v0, v1;
      if (pf) {
        const int kv1 = (t + 1) * 128;
        v0 = *(const u16x8*)(Vg + (size_t)(kv1 + 2*rp)*DHEAD + kc*8);
        v1 = *(const u16x8*)(Vg + (size_t)(kv1 + 2*rp + 1)*DHEAD + kc*8);
        #pragma unroll
        for (int h2 = 0; h2 < 2; ++h2)
          gll16(Kg + (size_t)(kv1 + 64*h2 + kkv)*DHEAD + kdc*8,
                smem + (cur^1)*8192 + h2*4096 + w*512);
      }

      if (t < ntw) {
        const u16* Kb = smem + cur*8192;
        const u16* Vv = smem + 16384 + cur*8192;

        // ---- S^T = K * Q^T ----
        f32x16 st[4] = {{}, {}, {}, {}};
        __builtin_amdgcn_s_setprio(1);
        #pragma unroll
        for (int kbg = 0; kbg < 4; ++kbg) {
          #pragma unroll
          for (int s = 0; s < 4; ++s) {
            const int slot = ((2*s + hi) ^ (l & 7) ^ ((4*(kbg & 1)) & 7) ^ (q5 >> 3)) & 7;
            const bf16x8 kf = *(const bf16x8*)(Kb + (kbg >> 1)*4096
                                               + ((kbg & 1)*32 + q5)*64 + slot*8);
            st[kbg] = __builtin_amdgcn_mfma_f32_32x32x16_bf16(kf, qf[s], st[kbg], 0, 0, 0);
          }
        }
        __builtin_amdgcn_s_setprio(0);

        // ---- causal mask (warp's diagonal tile only) ----
        if (t == ntw - 1) {
          const int kv0 = t * 128;
          #pragma unroll
          for (int kbg = 0; kbg < 4; ++kbg)
            #pragma unroll
            for (int rr = 0; rr < 16; ++rr) {
              const int kvg = kv0 + 32*kbg + (rr & 3) + 8*(rr >> 2) + 4*hi;
              if (kvg > q0w + q5) st[kbg][rr] = -1e30f;
            }
        }

        // ---- whole-tile max + defer + (rare) rescale BEFORE PV ----
        float mx = -1e30f;
        #pragma unroll
        for (int kbg = 0; kbg < 4; ++kbg)
          #pragma unroll
          for (int rr = 0; rr < 16; ++rr) mx = fmaxf(mx, st[kbg][rr]);
        mx = fmaxf(mx, __shfl_xor(mx, 32));
        float alpha = 1.0f;
        if (!__all(mx <= mrun + 8.0f)) {
          const float mnew = fmaxf(mrun, mx);
          alpha = __builtin_amdgcn_exp2f(mrun - mnew);
          mrun = mnew;
          #pragma unroll
          for (int rr = 0; rr < 16; ++rr) { c0[rr] *= alpha; c1[rr] *= alpha; }
        }

        float rs = 0.f;
        bf16x8 pb[8];

        // ---- slice A: exp+pack kbg0,1 -> pb[0..3] ----
        #pragma unroll
        for (int kbg = 0; kbg < 2; ++kbg) {
          #pragma unroll
          for (int rr = 0; rr < 16; ++rr) {
            const float pe = __builtin_amdgcn_exp2f(st[kbg][rr] - mrun);
            st[kbg][rr] = pe;
            rs += pe;
          }
          u32 pw[8];
          #pragma unroll
          for (int i = 0; i < 8; ++i) {
            u32 t0;
            asm("v_cvt_pk_bf16_f32 %0, %1, %2"
                : "=v"(t0) : "v"(st[kbg][2*i]), "v"(st[kbg][2*i+1]));
            pw[i] = t0;
          }
          asm("v_permlane32_swap_b32 %0, %1" : "+v"(pw[0]), "+v"(pw[2]));
          asm("v_permlane32_swap_b32 %0, %1" : "+v"(pw[1]), "+v"(pw[3]));
          asm("v_permlane32_swap_b32 %0, %1" : "+v"(pw[4]), "+v"(pw[6]));
          asm("v_permlane32_swap_b32 %0, %1" : "+v"(pw[5]), "+v"(pw[7]));
          pb[2*kbg]   = __builtin_bit_cast(bf16x8, u32x4{pw[0], pw[1], pw[2], pw[3]});
          pb[2*kbg+1] = __builtin_bit_cast(bf16x8, u32x4{pw[4], pw[5], pw[6], pw[7]});
        }

        // ---- PV sub-tile h2=0 (consumes pb[0..3]) ----
        #pragma unroll
        for (int s = 0; s < 4; ++s) {
          {
            const int slot = ((2*s + hi) ^ (l & 7) ^ (q5 >> 3)) & 7;
            const bf16x8 vf = *(const bf16x8*)(Vv + q5*64 + slot*8);
            c0 = __builtin_amdgcn_mfma_f32_32x32x16_bf16(vf, pb[s], c0, 0, 0, 0);
          }
          {
            const int slot = ((2*s + hi) ^ (l & 7) ^ 4 ^ (q5 >> 3)) & 7;
            const bf16x8 vf = *(const bf16x8*)(Vv + (32 + q5)*64 + slot*8);
            c1 = __builtin_amdgcn_mfma_f32_32x32x16_bf16(vf, pb[s], c1, 0, 0, 0);
          }
        }

        // ---- slice B: exp+pack kbg2,3 -> pb[4..7] (overlaps PV h2=0) ----
        #pragma unroll
        for (int kbg = 2; kbg < 4; ++kbg) {
          #pragma unroll
          for (int rr = 0; rr < 16; ++rr) {
            const float pe = __builtin_amdgcn_exp2f(st[kbg][rr] - mrun);
            st[kbg][rr] = pe;
            rs += pe;
          }
          u32 pw[8];
          #pragma unroll
          for (int i = 0; i < 8; ++i) {
            u32 t0;
            asm("v_cvt_pk_bf16_f32 %0, %1, %2"
                : "=v"(t0) : "v"(st[kbg][2*i]), "v"(st[kbg][2*i+1]));
            pw[i] = t0;
          }
          asm("v_permlane32_swap_b32 %0, %1" : "+v"(pw[0]), "+v"(pw[2]));
          asm("v_permlane32_swap_b32 %0, %1" : "+v"(pw[1]), "+v"(pw[3]));
          asm("v_permlane32_swap_b32 %0, %1" : "+v"(pw[4]), "+v"(pw[6]));
          asm("v_permlane32_swap_b32 %0, %1" : "+v"(pw[5]), "+v"(pw[7]));
          pb[2*kbg]   = __builtin_bit_cast(bf16x8, u32x4{pw[0], pw[1], pw[2], pw[3]});
          pb[2*kbg+1] = __builtin_bit_cast(bf16x8, u32x4{pw[4], pw[5], pw[6], pw[7]});
        }

        // ---- PV sub-tile h2=1 (consumes pb[4..7]) ----
        #pragma unroll
        for (int s = 0; s < 4; ++s) {
          {
            const int slot = ((2*s + hi) ^ (l & 7) ^ (q5 >> 3)) & 7;
            const bf16x8 vf = *(const bf16x8*)(Vv + 4096 + q5*64 + slot*8);
            c0 = __builtin_amdgcn_mfma_f32_32x32x16_bf16(vf, pb[4 + s], c0, 0, 0, 0);
          }
          {
            const int slot = ((2*s + hi) ^ (l & 7) ^ 4 ^ (q5 >> 3)) & 7;
            const bf16x8 vf = *(const bf16x8*)(Vv + 4096 + (32 + q5)*64 + slot*8);
            c1 = __builtin_amdgcn_mfma_f32_32x32x16_bf16(vf, pb[4 + s], c1, 0, 0, 0);
          }
        }

        rs += __shfl_xor(rs, 32);
        lrun = lrun * alpha + rs;
      }

      if (pf) {
        u32* Vd = (u32*)(smem + 16384) + (cur^1)*4096;
        #pragma unroll
        for (int e = 0; e < 8; ++e)
          Vd[vIdx32[e]] = (u32)v0[e] | ((u32)v1[e] << 16);
      }
      __syncthreads();
    }

    const float linv = __builtin_amdgcn_rcpf(lrun);
    #pragma unroll
    for (int Ab = 0; Ab < 2; ++Ab)
      #pragma unroll
      for (int rr = 0; rr < 16; ++rr) {
        const int d = 32*Ab + (rr & 3) + 8*(rr >> 2) + 4*hi;
        smem[w*2048 + q5*64 + (((d >> 3) ^ (q5 & 7)) & 7)*8 + (d & 7)] =
            f2bf((Ab ? c1[rr] : c0[rr]) * linv);
      }
    __syncthreads();
    #pragma unroll
    for (int cc = 0; cc < 4; ++cc) {
      const int dchunk = 4*hi + cc;
      const u16x8 vv = *(const u16x8*)&smem[w*2048 + q5*64 + ((dchunk ^ (q5 & 7)) & 7)*8];
      *(u16x8*)(Oa + (size_t)(b*SEQ + q0w + q5)*D_MODEL + h*DHEAD + 32*hi + 8*cc) = vv;
    }
    __syncthreads();
  }
}

extern "C" void kernel_launch(void* const* d_in, const int* in_sizes, int n_in,
                              void* d_out, int out_size, void* d_ws, size_t ws_size,
                              hipStream_t stream) {
  const float* X  = (const float*)d_in[0];
  const float* Wq = (const float*)d_in[1];
  const float* Wk = (const float*)d_in[2];
  const float* Wv = (const float*)d_in[3];
  const float* Wo = (const float*)d_in[4];

  u16* xb  = (u16*)d_ws;
  u16* wqb = xb  + (size_t)MTOT*D_MODEL;
  u16* wob = wqb + (size_t)3*D_MODEL*D_MODEL;
  u16* qkv = wob + (size_t)D_MODEL*D_MODEL;   // [3][B*H][S][64]
  u16* att = qkv + (size_t)3*MTOT*D_MODEL;    // [8192][1024]

  (void)hipFuncSetAttribute((const void*)gemm_qkv192,
                            hipFuncAttributeMaxDynamicSharedMemorySize, 114688);
  (void)hipFuncSetAttribute((const void*)gemm_o8p,
                            hipFuncAttributeMaxDynamicSharedMemorySize, 98304);

  cvtall<<<2048, 256, 0, stream>>>((const float4*)X,  (const float4*)Wq,
                                   (const float4*)Wk, (const float4*)Wv,
                                   (const float4*)Wo, (u16x4*)xb);

  gemm_qkv192<<<512, 512, 114688, stream>>>(xb, wqb, qkv);

  attn9_k<<<256, 512, 0, stream>>>(qkv, qkv + (size_t)MTOT*D_MODEL,
                                   qkv + (size_t)2*MTOT*D_MODEL, att);

  gemm_o8p<<<256, 512, 98304, stream>>>(att, wob, (float*)d_out);
}